// Round 4
// baseline (56.221 us; speedup 1.0000x reference)
//
#include <hip/hip_runtime.h>
#include <math.h>

#define N_PTS   8192
#define BATCH   2
#define NTHR    256
#define QPT     8                       // queries per thread (registers)
#define QPB     (NTHR * QPT)            // 2048 queries per block
#define NQB     (N_PTS / QPB)           // 4 query-blocks per (b,dir)
#define NCHUNK  64
#define CHUNKC  (N_PTS / NCHUNK)        // 128 candidates per chunk
#define TOTQ    (BATCH * 2 * N_PTS)     // 32768 query slots
#define RBLK    (TOTQ / 256)            // 128 reduce blocks

// ws layout:
//   cand  : float4[2][BATCH][N_PTS]  set0 = pc2, set1 = pc1+flow      (512 KB)
//           cand[i] = (-2px, -2py, -2pz, |p|^2)
//   res   : float[NCHUNK][TOTQ]      per-chunk min d^2                 (8 MB)
//   accum : float
//   counter: uint

__global__ __launch_bounds__(256) void chamfer_prep(const float* __restrict__ pc1,
                                                    const float* __restrict__ pc2,
                                                    const float* __restrict__ flow,
                                                    float4* __restrict__ cand,
                                                    float* __restrict__ accum,
                                                    unsigned int* __restrict__ counter) {
    int i = blockIdx.x * 256 + threadIdx.x;          // 0 .. BATCH*N_PTS-1
    if (i < BATCH * N_PTS) {
        float px = pc2[i * 3 + 0], py = pc2[i * 3 + 1], pz = pc2[i * 3 + 2];
        cand[i] = make_float4(-2.f * px, -2.f * py, -2.f * pz,
                              px * px + py * py + pz * pz);
        float wx = pc1[i * 3 + 0] + flow[i * 3 + 0];
        float wy = pc1[i * 3 + 1] + flow[i * 3 + 1];
        float wz = pc1[i * 3 + 2] + flow[i * 3 + 2];
        cand[BATCH * N_PTS + i] = make_float4(-2.f * wx, -2.f * wy, -2.f * wz,
                                              wx * wx + wy * wy + wz * wz);
    }
    if (i == 0) { *accum = 0.0f; *counter = 0u; }
}

__global__ __launch_bounds__(NTHR) void chamfer_nn(const float4* __restrict__ cand,
                                                   float* __restrict__ res) {
    const int qb    = blockIdx.x % NQB;
    const int chunk = blockIdx.x / NQB;
    const int b     = blockIdx.y;
    const int dir   = blockIdx.z;   // 0: q=warped, db=pc2;  1: q=pc2, db=warped

    const float4* __restrict__ qarr =
        cand + ((size_t)(1 - dir) * BATCH + b) * N_PTS;
    const float4* __restrict__ db =
        cand + ((size_t)dir * BATCH + b) * N_PTS + (size_t)chunk * CHUNKC;

    const int q0 = qb * QPB + threadIdx.x;

    float qx[QPT], qy[QPT], qz[QPT], q2[QPT], m[QPT];
    #pragma unroll
    for (int k = 0; k < QPT; ++k) {
        float4 c = qarr[q0 + k * NTHR];
        qx[k] = -0.5f * c.x;
        qy[k] = -0.5f * c.y;
        qz[k] = -0.5f * c.z;
        q2[k] = c.w;
        m[k]  = 3.402823466e38f;
    }

    // Wave-uniform candidate stream -> s_load_dwordx4; ~33 VALU per candidate.
    #pragma unroll 8
    for (int j = 0; j < CHUNKC; ++j) {
        float4 c = db[j];
        #pragma unroll
        for (int k = 0; k < QPT; ++k) {
            float t = fmaf(qz[k], c.z, c.w);
            t = fmaf(qy[k], c.y, t);
            t = fmaf(qx[k], c.x, t);
            m[k] = fminf(m[k], t);
        }
    }

    float* __restrict__ dst =
        res + (size_t)chunk * TOTQ + ((size_t)dir * BATCH + b) * N_PTS;
    #pragma unroll
    for (int k = 0; k < QPT; ++k)
        dst[q0 + k * NTHR] = fmaxf(m[k] + q2[k], 0.0f);
}

__global__ __launch_bounds__(256) void chamfer_reduce(const float* __restrict__ res,
                                                      float* __restrict__ accum,
                                                      unsigned int* __restrict__ counter,
                                                      float* __restrict__ out) {
    const int i = blockIdx.x * 256 + threadIdx.x;   // < TOTQ
    float m = res[i];
    #pragma unroll 8
    for (int c = 1; c < NCHUNK; ++c)
        m = fminf(m, res[(size_t)c * TOTQ + i]);
    float v = sqrtf(m);

    for (int off = 32; off > 0; off >>= 1)
        v += __shfl_down(v, off, 64);

    __shared__ float wsum[4];
    const int wave = threadIdx.x >> 6;
    if ((threadIdx.x & 63) == 0) wsum[wave] = v;
    __syncthreads();
    if (threadIdx.x == 0) {
        atomicAdd(accum, wsum[0] + wsum[1] + wsum[2] + wsum[3]);
        __threadfence();
        unsigned int old = atomicAdd(counter, 1u);
        if (old == RBLK - 1) {
            float total = atomicAdd(accum, 0.0f);   // coherent read after all adds
            out[0] = total * (1.0f / (float)(BATCH * N_PTS));
        }
    }
}

extern "C" void kernel_launch(void* const* d_in, const int* in_sizes, int n_in,
                              void* d_out, int out_size, void* d_ws, size_t ws_size,
                              hipStream_t stream) {
    const float* pc1  = (const float*)d_in[0];
    const float* pc2  = (const float*)d_in[1];
    const float* flow = (const float*)d_in[2];
    float* out = (float*)d_out;

    float4* cand = (float4*)d_ws;
    float*  res  = (float*)(cand + 2 * BATCH * N_PTS);
    float*  accum = res + (size_t)NCHUNK * TOTQ;
    unsigned int* counter = (unsigned int*)(accum + 1);

    chamfer_prep<<<(BATCH * N_PTS + 255) / 256, 256, 0, stream>>>(pc1, pc2, flow,
                                                                  cand, accum, counter);

    dim3 grid(NQB * NCHUNK, BATCH, 2);
    chamfer_nn<<<grid, NTHR, 0, stream>>>(cand, res);

    chamfer_reduce<<<RBLK, 256, 0, stream>>>(res, accum, counter, out);
}